// Round 1
// baseline (790.649 us; speedup 1.0000x reference)
//
#include <hip/hip_runtime.h>
#include <hip/hip_bf16.h>

#define DIM 256
#define PROJ 128
#define NPOS 8
#define KDIM 136
#define HEADS 4
#define HD 64
#define EPS 1e-5f

// ---------------- build src = concat(input, pos) ----------------
__global__ __launch_bounds__(256) void build_src(const float* __restrict__ input,
                                                 float* __restrict__ src, int L) {
    int idx = blockIdx.x * 256 + threadIdx.x;
    int total = L * KDIM;
    if (idx >= total) return;
    int n = idx / KDIM, c = idx % KDIM;
    float v;
    if (c < PROJ) {
        v = input[(size_t)n * PROJ + c];
    } else {
        int i = c - PROJ;                      // 0..7
        int mask = (2 << i) - 1;               // 2^(i+1)-1
        v = (float)(n & mask) / (float)(1 << i);
    }
    src[idx] = v;
}

// ---------------- generic C = A(MxK) @ B(NxK)^T + bias ----------------
__global__ __launch_bounds__(256) void gemm_bt(const float* __restrict__ A,
                                               const float* __restrict__ B,
                                               const float* __restrict__ bias,
                                               float* __restrict__ C,
                                               int M, int N, int K) {
    __shared__ float As[32][33];
    __shared__ float Bs[32][33];
    int tx = threadIdx.x % 16, ty = threadIdx.x / 16;
    int block_m = blockIdx.y * 32, block_n = blockIdx.x * 32;
    float acc[2][2] = {{0.f, 0.f}, {0.f, 0.f}};
    for (int k0 = 0; k0 < K; k0 += 32) {
        for (int idx = threadIdx.x; idx < 32 * 32; idx += 256) {
            int r = idx / 32, c = idx % 32;
            int m = block_m + r, kk = k0 + c;
            As[r][c] = (m < M && kk < K) ? A[(size_t)m * K + kk] : 0.f;
            int n = block_n + r;
            Bs[r][c] = (n < N && kk < K) ? B[(size_t)n * K + kk] : 0.f;
        }
        __syncthreads();
        #pragma unroll
        for (int kk = 0; kk < 32; ++kk) {
            float a0 = As[ty * 2 + 0][kk], a1 = As[ty * 2 + 1][kk];
            float b0 = Bs[tx * 2 + 0][kk], b1 = Bs[tx * 2 + 1][kk];
            acc[0][0] += a0 * b0; acc[0][1] += a0 * b1;
            acc[1][0] += a1 * b0; acc[1][1] += a1 * b1;
        }
        __syncthreads();
    }
    #pragma unroll
    for (int i = 0; i < 2; ++i)
        #pragma unroll
        for (int j = 0; j < 2; ++j) {
            int m = block_m + ty * 2 + i, n = block_n + tx * 2 + j;
            if (m < M && n < N)
                C[(size_t)m * N + n] = acc[i][j] + bias[n];
        }
}

// ---------------- banded multihead attention ----------------
// grid = T blocks; block = 256 threads = 4 waves; wave h handles head h of row j.
__global__ __launch_bounds__(256) void attn_banded(const float* __restrict__ q,
                                                   const float* __restrict__ k,
                                                   const float* __restrict__ v,
                                                   float* __restrict__ ctx,
                                                   int T, int L) {
    int j = blockIdx.x;
    int col = threadIdx.x;          // h*64 + d
    float qv = q[(size_t)j * DIM + col] * 0.125f;   // 1/sqrt(64)

    int ilo = (j >= 68) ? (j - 64) / 5 : 0;         // ceil((j-68)/5) clamped
    int ihi = (j + 64) / 5;
    if (ihi > L - 1) ihi = L - 1;

    const int WMAX = 27;
    float sc[WMAX];
    #pragma unroll
    for (int t = 0; t < WMAX; ++t) {
        int i = ilo + t;
        float s = -1e30f;
        if (i <= ihi) {
            float p = qv * k[(size_t)i * DIM + col];
            #pragma unroll
            for (int m = 32; m > 0; m >>= 1) p += __shfl_xor(p, m, 64);
            s = p;
        }
        sc[t] = s;
    }
    float mx = -1e30f;
    #pragma unroll
    for (int t = 0; t < WMAX; ++t) mx = fmaxf(mx, sc[t]);
    float den = 0.f, o = 0.f;
    #pragma unroll
    for (int t = 0; t < WMAX; ++t) {
        int i = ilo + t;
        if (i <= ihi) {
            float p = expf(sc[t] - mx);
            den += p;
            o += p * v[(size_t)i * DIM + col];
        }
    }
    ctx[(size_t)j * DIM + col] = o / den;
}

// ---------------- LayerNorm(x) + res ----------------
__global__ __launch_bounds__(256) void ln_add(const float* __restrict__ x,
                                              const float* __restrict__ res,
                                              float* __restrict__ y, int T) {
    __shared__ float red[8];
    int row = blockIdx.x, c = threadIdx.x;
    float v = x[(size_t)row * DIM + c];
    float s = v;
    #pragma unroll
    for (int m = 32; m > 0; m >>= 1) s += __shfl_xor(s, m, 64);
    int wid = c >> 6, lane = c & 63;
    if (lane == 0) red[wid] = s;
    __syncthreads();
    float mu = (red[0] + red[1] + red[2] + red[3]) * (1.f / 256.f);
    float d = v - mu;
    float s2 = d * d;
    #pragma unroll
    for (int m = 32; m > 0; m >>= 1) s2 += __shfl_xor(s2, m, 64);
    if (lane == 0) red[4 + wid] = s2;
    __syncthreads();
    float var = (red[4] + red[5] + red[6] + red[7]) * (1.f / 256.f);
    y[(size_t)row * DIM + c] = d * rsqrtf(var + EPS) + res[(size_t)row * DIM + c];
}

// ---------------- LayerNorm(a + b) ----------------
__global__ __launch_bounds__(256) void ln_sum(const float* __restrict__ a,
                                              const float* __restrict__ b,
                                              float* __restrict__ y, int T) {
    __shared__ float red[8];
    int row = blockIdx.x, c = threadIdx.x;
    float v = a[(size_t)row * DIM + c] + b[(size_t)row * DIM + c];
    float s = v;
    #pragma unroll
    for (int m = 32; m > 0; m >>= 1) s += __shfl_xor(s, m, 64);
    int wid = c >> 6, lane = c & 63;
    if (lane == 0) red[wid] = s;
    __syncthreads();
    float mu = (red[0] + red[1] + red[2] + red[3]) * (1.f / 256.f);
    float d = v - mu;
    float s2 = d * d;
    #pragma unroll
    for (int m = 32; m > 0; m >>= 1) s2 += __shfl_xor(s2, m, 64);
    if (lane == 0) red[4 + wid] = s2;
    __syncthreads();
    float var = (red[4] + red[5] + red[6] + red[7]) * (1.f / 256.f);
    y[(size_t)row * DIM + c] = d * rsqrtf(var + EPS);
}

// ---------------- conv1d(k=3,pad=1) + bias + tanh ----------------
// in/out: (T, 256) row-major. W: (256 out, 256 in, 3). One block = 16 timesteps.
#define CT 16
__global__ __launch_bounds__(256) void conv3_tanh(const float* __restrict__ in,
                                                  const float* __restrict__ W,
                                                  const float* __restrict__ b,
                                                  float* __restrict__ out, int T) {
    __shared__ float xs[CT + 2][DIM];
    int t0 = blockIdx.x * CT;
    int o = threadIdx.x;   // output channel
    #pragma unroll
    for (int r = 0; r < CT + 2; ++r) {
        int t = t0 - 1 + r;
        xs[r][o] = (t >= 0 && t < T) ? in[(size_t)t * DIM + o] : 0.f;
    }
    __syncthreads();
    float acc[CT];
    float bo = b[o];
    #pragma unroll
    for (int t = 0; t < CT; ++t) acc[t] = bo;
    #pragma unroll 4
    for (int ci = 0; ci < DIM; ++ci) {
        float w0 = W[((size_t)o * DIM + ci) * 3 + 0];
        float w1 = W[((size_t)o * DIM + ci) * 3 + 1];
        float w2 = W[((size_t)o * DIM + ci) * 3 + 2];
        #pragma unroll
        for (int t = 0; t < CT; ++t) {
            acc[t] += xs[t][ci] * w0 + xs[t + 1][ci] * w1 + xs[t + 2][ci] * w2;
        }
    }
    #pragma unroll
    for (int t = 0; t < CT; ++t)
        out[(size_t)(t0 + t) * DIM + o] = tanhf(acc[t]);
}

extern "C" void kernel_launch(void* const* d_in, const int* in_sizes, int n_in,
                              void* d_out, int out_size, void* d_ws, size_t ws_size,
                              hipStream_t stream) {
    const float* input    = (const float*)d_in[0];
    const float* residual = (const float*)d_in[1];
    const float* W_proj   = (const float*)d_in[2];
    const float* b_proj   = (const float*)d_in[3];
    const float* Wq       = (const float*)d_in[4];
    const float* bq       = (const float*)d_in[5];
    const float* Wk       = (const float*)d_in[6];
    const float* bk       = (const float*)d_in[7];
    const float* Wv       = (const float*)d_in[8];
    const float* bv       = (const float*)d_in[9];
    const float* Wo       = (const float*)d_in[10];
    const float* bo       = (const float*)d_in[11];
    const float* conv_w   = (const float*)d_in[12];
    const float* conv_b   = (const float*)d_in[13];
    const float* W_skip   = (const float*)d_in[14];
    const float* b_skip   = (const float*)d_in[15];
    float* out = (float*)d_out;
    float* ws  = (float*)d_ws;

    const int L = in_sizes[0] / PROJ;   // 2048
    const int T = 5 * L;                // 10240

    // workspace layout (floats)
    float* src = ws;                              // L*KDIM (padded to 524288)
    float* B1  = ws + 524288;                     // T*256  (tgt / ctx / cnn_in)
    float* B2  = B1 + (size_t)T * DIM;            // T*256  (q / attn_out / conv ping / skip)
    float* B3  = B2 + (size_t)T * DIM;            // L*256  (k)
    float* B4  = B3 + (size_t)L * DIM;            // L*256  (v)
    float* B5  = B4 + (size_t)L * DIM;            // T*256  (conv pong)

    // 1) src = concat(input, pos)
    build_src<<<dim3((L * KDIM + 255) / 256), dim3(256), 0, stream>>>(input, src, L);

    // 2) tgt = src @ W_proj^T + b_proj   -> (L,1280) == (T,256) row-major
    gemm_bt<<<dim3((5 * DIM + 31) / 32, (L + 31) / 32), dim3(256), 0, stream>>>(
        src, W_proj, b_proj, B1, L, 5 * DIM, KDIM);

    // 3) q = tgt @ Wq^T + bq
    gemm_bt<<<dim3(DIM / 32, (T + 31) / 32), dim3(256), 0, stream>>>(
        B1, Wq, bq, B2, T, DIM, DIM);

    // 4) k = src @ Wk^T + bk ; v = src @ Wv^T + bv
    gemm_bt<<<dim3(DIM / 32, (L + 31) / 32), dim3(256), 0, stream>>>(
        src, Wk, bk, B3, L, DIM, KDIM);
    gemm_bt<<<dim3(DIM / 32, (L + 31) / 32), dim3(256), 0, stream>>>(
        src, Wv, bv, B4, L, DIM, KDIM);

    // 5) banded attention -> ctx (overwrites B1; tgt dead after q)
    attn_banded<<<dim3(T), dim3(256), 0, stream>>>(B2, B3, B4, B1, T, L);

    // 6) attn_out = ctx @ Wo^T + bo  (into B2; q dead)
    gemm_bt<<<dim3(DIM / 32, (T + 31) / 32), dim3(256), 0, stream>>>(
        B1, Wo, bo, B2, T, DIM, DIM);

    // 7) cnn_in = LN(attn_out) + residual  (into B1; ctx dead)
    ln_add<<<dim3(T), dim3(256), 0, stream>>>(B2, residual, B1, T);

    // 8) conv stack: B1 -> B2 -> B5 -> B2 -> B5
    const size_t WSTRIDE = (size_t)DIM * DIM * 3;
    conv3_tanh<<<dim3(T / CT), dim3(256), 0, stream>>>(B1, conv_w + 0 * WSTRIDE, conv_b + 0 * DIM, B2, T);
    conv3_tanh<<<dim3(T / CT), dim3(256), 0, stream>>>(B2, conv_w + 1 * WSTRIDE, conv_b + 1 * DIM, B5, T);
    conv3_tanh<<<dim3(T / CT), dim3(256), 0, stream>>>(B5, conv_w + 2 * WSTRIDE, conv_b + 2 * DIM, B2, T);
    conv3_tanh<<<dim3(T / CT), dim3(256), 0, stream>>>(B2, conv_w + 3 * WSTRIDE, conv_b + 3 * DIM, B5, T);

    // 9) skip = cnn_in @ W_skip^T + b_skip  (into B2; conv done reading it)
    gemm_bt<<<dim3(DIM / 32, (T + 31) / 32), dim3(256), 0, stream>>>(
        B1, W_skip, b_skip, B2, T, DIM, DIM);

    // 10) out = LN(cnn_out + skip)
    ln_sum<<<dim3(T), dim3(256), 0, stream>>>(B5, B2, out, T);
}

// Round 2
// 164.213 us; speedup vs baseline: 4.8148x; 4.8148x over previous
//
#include <hip/hip_runtime.h>
#include <hip/hip_bf16.h>

#define PROJ 128
#define KPAD 192
#define EPS 1e-5f

typedef __attribute__((ext_vector_type(4))) float f32x4;
typedef __attribute__((ext_vector_type(8))) short bf16x8;
typedef __attribute__((ext_vector_type(4))) unsigned int u32x4;

__device__ inline float bflo(unsigned u){ union{unsigned x;float f;}c; c.x = u<<16; return c.f; }
__device__ inline float bfhi(unsigned u){ union{unsigned x;float f;}c; c.x = u & 0xffff0000u; return c.f; }
__device__ inline float bf2f(unsigned short u){ union{unsigned x;float f;}c; c.x = ((unsigned)u)<<16; return c.f; }
__device__ inline unsigned short f2bf(float f){
    union{float f; unsigned u;} c; c.f = f;
    unsigned r = c.u + 0x7fff + ((c.u >> 16) & 1);
    return (unsigned short)(r >> 16);
}

// ---------------- weight conversion ----------------
__global__ __launch_bounds__(256) void convert_pad(const float* __restrict__ W,
                                                   unsigned short* __restrict__ out,
                                                   int rows, int inc, int outc) {
    int idx = blockIdx.x * 256 + threadIdx.x;
    if (idx >= rows * outc) return;
    int r = idx / outc, c = idx % outc;
    out[idx] = (c < inc) ? f2bf(W[(size_t)r * inc + c]) : (unsigned short)0;
}

// conv_w (l, o, ci, kt) -> (l, o, kt*256+ci) bf16
__global__ __launch_bounds__(256) void convw_reorder(const float* __restrict__ w,
                                                     unsigned short* __restrict__ out) {
    int idx = blockIdx.x * 256 + threadIdx.x;
    if (idx >= 4 * 256 * 768) return;
    int l = idx / 196608;
    int r = idx % 196608;
    int o = r / 768, kc = r % 768;
    int kt = kc / 256, ci = kc % 256;
    out[idx] = f2bf(w[(((size_t)l * 256 + o) * 256 + ci) * 3 + kt]);
}

__global__ __launch_bounds__(256) void zero_pads(unsigned short* a, unsigned short* b,
                                                 unsigned short* c, int T) {
    int t = threadIdx.x;
    a[t] = 0; a[(size_t)(T + 1) * 256 + t] = 0;
    b[t] = 0; b[(size_t)(T + 1) * 256 + t] = 0;
    c[t] = 0; c[(size_t)(T + 1) * 256 + t] = 0;
}

// ---------------- src = concat(input, pos) zero-padded to 192, bf16 ----------------
__global__ __launch_bounds__(256) void build_src_bf(const float* __restrict__ input,
                                                    unsigned short* __restrict__ src, int L) {
    int idx = blockIdx.x * 256 + threadIdx.x;
    if (idx >= L * KPAD) return;
    int n = idx / KPAD, c = idx % KPAD;
    float v = 0.f;
    if (c < PROJ) v = input[(size_t)n * PROJ + c];
    else if (c < PROJ + 8) {
        int i = c - PROJ;
        int mask = (2 << i) - 1;
        v = (float)(n & mask) / (float)(1 << i);
    }
    src[idx] = f2bf(v);
}

// ---------------- bf16 MFMA GEMM: C = A(MxK,lda) @ B(NxK,ldb)^T + bias ----------------
// tile 64x128, BK=64, 4 waves (2m x 2n), each wave 32x64 via 2x4 frags of 16x16x32
template<bool TANH>
__global__ __launch_bounds__(256) void gemm_bf16(
    const unsigned short* __restrict__ A, int lda,
    const unsigned short* __restrict__ B, int ldb,
    const float* __restrict__ bias,
    unsigned short* __restrict__ C, int ldc,
    int M, int N, int K)
{
    __shared__ unsigned short As[64][72];
    __shared__ unsigned short Bs[128][72];
    const int tid = threadIdx.x;
    const int lane = tid & 63;
    const int wid = tid >> 6;
    const int wm = wid >> 1, wn = wid & 1;
    const int m0 = blockIdx.y * 64, n0 = blockIdx.x * 128;

    const int ar = tid >> 2, asg = tid & 3;   // A tile: 64 rows x 4 segs of 16
    const int br = tid >> 1, bsg = tid & 1;   // B tile: 128 rows x 2 segs of 32

    const unsigned short* Ap = A + (size_t)(m0 + ar) * lda + asg * 16;
    const unsigned short* Bp = B + (size_t)(n0 + br) * ldb + bsg * 32;

    u32x4 ra0, ra1, rb0, rb1, rb2, rb3;
    auto loadregs = [&](int k0) {
        ra0 = *(const u32x4*)(Ap + k0);
        ra1 = *(const u32x4*)(Ap + k0 + 8);
        rb0 = *(const u32x4*)(Bp + k0);
        rb1 = *(const u32x4*)(Bp + k0 + 8);
        rb2 = *(const u32x4*)(Bp + k0 + 16);
        rb3 = *(const u32x4*)(Bp + k0 + 24);
    };
    auto stlds = [&]() {
        *(u32x4*)&As[ar][asg * 16]      = ra0;
        *(u32x4*)&As[ar][asg * 16 + 8]  = ra1;
        *(u32x4*)&Bs[br][bsg * 32]      = rb0;
        *(u32x4*)&Bs[br][bsg * 32 + 8]  = rb1;
        *(u32x4*)&Bs[br][bsg * 32 + 16] = rb2;
        *(u32x4*)&Bs[br][bsg * 32 + 24] = rb3;
    };

    f32x4 acc[2][4];
    #pragma unroll
    for (int i = 0; i < 2; ++i)
        #pragma unroll
        for (int j = 0; j < 4; ++j) acc[i][j] = (f32x4){0.f, 0.f, 0.f, 0.f};

    loadregs(0);
    stlds();
    __syncthreads();

    const int rowf = lane & 15, kb = lane >> 4;
    const int ktiles = K >> 6;
    for (int kt = 0; kt < ktiles; ++kt) {
        if (kt + 1 < ktiles) loadregs((kt + 1) << 6);
        #pragma unroll
        for (int ks = 0; ks < 2; ++ks) {
            bf16x8 af[2], bfr[4];
            #pragma unroll
            for (int i = 0; i < 2; ++i)
                af[i] = *(const bf16x8*)&As[wm * 32 + i * 16 + rowf][ks * 32 + kb * 8];
            #pragma unroll
            for (int j = 0; j < 4; ++j)
                bfr[j] = *(const bf16x8*)&Bs[wn * 64 + j * 16 + rowf][ks * 32 + kb * 8];
            #pragma unroll
            for (int i = 0; i < 2; ++i)
                #pragma unroll
                for (int j = 0; j < 4; ++j)
                    acc[i][j] = __builtin_amdgcn_mfma_f32_16x16x32_bf16(af[i], bfr[j], acc[i][j], 0, 0, 0);
        }
        __syncthreads();
        if (kt + 1 < ktiles) { stlds(); __syncthreads(); }
    }

    const int rq = lane >> 4;
    #pragma unroll
    for (int i = 0; i < 2; ++i) {
        int gm = m0 + wm * 32 + i * 16 + rq * 4;
        #pragma unroll
        for (int j = 0; j < 4; ++j) {
            int gn = n0 + wn * 64 + j * 16 + rowf;
            float bv = bias[gn];
            #pragma unroll
            for (int r = 0; r < 4; ++r) {
                float vv = acc[i][j][r] + bv;
                if (TANH) vv = 1.f - 2.f / (__expf(2.f * vv) + 1.f);
                C[(size_t)(gm + r) * ldc + gn] = f2bf(vv);
            }
        }
    }
}

// ---------------- banded attention: block = 16 queries, LDS-staged K/V window ----------------
__global__ __launch_bounds__(256) void attn16(
    const unsigned short* __restrict__ q,
    const unsigned short* __restrict__ k,
    const unsigned short* __restrict__ v,
    unsigned short* __restrict__ ctx, int L)
{
    __shared__ unsigned short ksm[30][264];
    __shared__ unsigned short vsm[30][264];
    const int j0 = blockIdx.x * 16;
    const int iblk0 = (j0 >= 68) ? (j0 - 64) / 5 : 0;
    int ihim = (j0 + 79) / 5; if (ihim > L - 1) ihim = L - 1;
    const int NR = ihim - iblk0 + 1;                 // <= 30

    for (int e = threadIdx.x; e < 30 * 32; e += 256) {
        int rr = e >> 5, cc = (e & 31) * 8;
        u32x4 kz = {0, 0, 0, 0}, vz = {0, 0, 0, 0};
        if (rr < NR) {
            kz = *(const u32x4*)&k[(size_t)(iblk0 + rr) * 256 + cc];
            vz = *(const u32x4*)&v[(size_t)(iblk0 + rr) * 256 + cc];
        }
        *(u32x4*)&ksm[rr][cc] = kz;
        *(u32x4*)&vsm[rr][cc] = vz;
    }
    __syncthreads();

    const int tid = threadIdx.x;
    const int h = tid >> 6, lane = tid & 63;
    const int qq = lane & 15, p = lane >> 4;
    const int j = j0 + qq;
    const int colb = h * 64 + p * 16;

    float qr[16];
    {
        u32x4 q0 = *(const u32x4*)&q[(size_t)j * 256 + colb];
        u32x4 q1 = *(const u32x4*)&q[(size_t)j * 256 + colb + 8];
        #pragma unroll
        for (int w = 0; w < 4; ++w) {
            qr[2 * w]     = bflo(q0[w]) * 0.125f;
            qr[2 * w + 1] = bfhi(q0[w]) * 0.125f;
            qr[8 + 2 * w]     = bflo(q1[w]) * 0.125f;
            qr[8 + 2 * w + 1] = bfhi(q1[w]) * 0.125f;
        }
    }
    const int ilo = (j >= 68) ? (j - 64) / 5 : 0;
    int ihi = (j + 64) / 5; if (ihi > L - 1) ihi = L - 1;

    float sc[30];
    #pragma unroll
    for (int t = 0; t < 30; ++t) {
        int i = iblk0 + t;
        u32x4 k0 = *(const u32x4*)&ksm[t][colb];
        u32x4 k1 = *(const u32x4*)&ksm[t][colb + 8];
        float s = 0.f;
        #pragma unroll
        for (int w = 0; w < 4; ++w) {
            s += qr[2 * w]     * bflo(k0[w]);
            s += qr[2 * w + 1] * bfhi(k0[w]);
            s += qr[8 + 2 * w]     * bflo(k1[w]);
            s += qr[8 + 2 * w + 1] * bfhi(k1[w]);
        }
        s += __shfl_xor(s, 16, 64);
        s += __shfl_xor(s, 32, 64);
        sc[t] = (i >= ilo && i <= ihi) ? s : -1e30f;
    }
    float mx = -1e30f;
    #pragma unroll
    for (int t = 0; t < 30; ++t) mx = fmaxf(mx, sc[t]);
    float den = 0.f, o[16];
    #pragma unroll
    for (int d = 0; d < 16; ++d) o[d] = 0.f;
    #pragma unroll
    for (int t = 0; t < 30; ++t) {
        float pt = __expf(sc[t] - mx);
        den += pt;
        u32x4 v0 = *(const u32x4*)&vsm[t][colb];
        u32x4 v1 = *(const u32x4*)&vsm[t][colb + 8];
        #pragma unroll
        for (int w = 0; w < 4; ++w) {
            o[2 * w]     += pt * bflo(v0[w]);
            o[2 * w + 1] += pt * bfhi(v0[w]);
            o[8 + 2 * w]     += pt * bflo(v1[w]);
            o[8 + 2 * w + 1] += pt * bfhi(v1[w]);
        }
    }
    float inv = 1.f / den;
    #pragma unroll
    for (int d = 0; d < 16; ++d)
        ctx[(size_t)j * 256 + colb + d] = f2bf(o[d] * inv);
}

// ---------------- LayerNorm(x_bf16) + res_f32 -> bf16 ----------------
__global__ __launch_bounds__(256) void ln_add_bf(const unsigned short* __restrict__ x,
                                                 const float* __restrict__ res,
                                                 unsigned short* __restrict__ y) {
    __shared__ float red[8];
    int row = blockIdx.x, c = threadIdx.x;
    float v = bf2f(x[(size_t)row * 256 + c]);
    float s = v;
    #pragma unroll
    for (int m = 32; m > 0; m >>= 1) s += __shfl_xor(s, m, 64);
    int wid = c >> 6, lanei = c & 63;
    if (lanei == 0) red[wid] = s;
    __syncthreads();
    float mu = (red[0] + red[1] + red[2] + red[3]) * (1.f / 256.f);
    float d = v - mu;
    float s2 = d * d;
    #pragma unroll
    for (int m = 32; m > 0; m >>= 1) s2 += __shfl_xor(s2, m, 64);
    if (lanei == 0) red[4 + wid] = s2;
    __syncthreads();
    float var = (red[4] + red[5] + red[6] + red[7]) * (1.f / 256.f);
    y[(size_t)row * 256 + c] = f2bf(d * rsqrtf(var + EPS) + res[(size_t)row * 256 + c]);
}

// ---------------- LayerNorm(a_bf16 + b_bf16) -> f32 ----------------
__global__ __launch_bounds__(256) void ln_sum_bf(const unsigned short* __restrict__ a,
                                                 const unsigned short* __restrict__ b,
                                                 float* __restrict__ y) {
    __shared__ float red[8];
    int row = blockIdx.x, c = threadIdx.x;
    float v = bf2f(a[(size_t)row * 256 + c]) + bf2f(b[(size_t)row * 256 + c]);
    float s = v;
    #pragma unroll
    for (int m = 32; m > 0; m >>= 1) s += __shfl_xor(s, m, 64);
    int wid = c >> 6, lanei = c & 63;
    if (lanei == 0) red[wid] = s;
    __syncthreads();
    float mu = (red[0] + red[1] + red[2] + red[3]) * (1.f / 256.f);
    float d = v - mu;
    float s2 = d * d;
    #pragma unroll
    for (int m = 32; m > 0; m >>= 1) s2 += __shfl_xor(s2, m, 64);
    if (lanei == 0) red[4 + wid] = s2;
    __syncthreads();
    float var = (red[4] + red[5] + red[6] + red[7]) * (1.f / 256.f);
    y[(size_t)row * 256 + c] = d * rsqrtf(var + EPS);
}

extern "C" void kernel_launch(void* const* d_in, const int* in_sizes, int n_in,
                              void* d_out, int out_size, void* d_ws, size_t ws_size,
                              hipStream_t stream) {
    const float* input    = (const float*)d_in[0];
    const float* residual = (const float*)d_in[1];
    const float* W_proj   = (const float*)d_in[2];
    const float* b_proj   = (const float*)d_in[3];
    const float* Wq       = (const float*)d_in[4];
    const float* bq       = (const float*)d_in[5];
    const float* Wk       = (const float*)d_in[6];
    const float* bk       = (const float*)d_in[7];
    const float* Wv       = (const float*)d_in[8];
    const float* bv       = (const float*)d_in[9];
    const float* Wo       = (const float*)d_in[10];
    const float* bo       = (const float*)d_in[11];
    const float* conv_w   = (const float*)d_in[12];
    const float* conv_b   = (const float*)d_in[13];
    const float* W_skip   = (const float*)d_in[14];
    const float* b_skip   = (const float*)d_in[15];
    float* out = (float*)d_out;

    const int L = in_sizes[0] / PROJ;   // 2048
    const int T = 5 * L;                // 10240

    unsigned short* w16 = (unsigned short*)d_ws;
    size_t off = 0;
    auto alloc = [&](size_t n) { unsigned short* p = w16 + off; off += n; return p; };
    unsigned short* srcb = alloc((size_t)L * KPAD);
    unsigned short* Wpb  = alloc((size_t)1280 * 192);
    unsigned short* Wqb  = alloc(256 * 256);
    unsigned short* Wkb  = alloc(256 * 192);
    unsigned short* Wvb  = alloc(256 * 192);
    unsigned short* Wob  = alloc(256 * 256);
    unsigned short* Wsb  = alloc(256 * 256);
    unsigned short* Wcb  = alloc((size_t)4 * 256 * 768);
    unsigned short* tgtb = alloc((size_t)T * 256);       // tgt, then ctx
    unsigned short* qb   = alloc((size_t)T * 256);       // q, then attn_out
    unsigned short* kb   = alloc((size_t)L * 256);
    unsigned short* vb   = alloc((size_t)L * 256);
    unsigned short* cinp = alloc((size_t)(T + 2) * 256); // padded cnn_in
    unsigned short* p1   = alloc((size_t)(T + 2) * 256); // conv ping, then skip
    unsigned short* p2   = alloc((size_t)(T + 2) * 256); // conv pong

    // weight conversion + pads
    convert_pad<<<dim3((1280 * 192 + 255) / 256), 256, 0, stream>>>(W_proj, Wpb, 1280, 136, 192);
    convert_pad<<<dim3((256 * 256 + 255) / 256), 256, 0, stream>>>(Wq, Wqb, 256, 256, 256);
    convert_pad<<<dim3((256 * 192 + 255) / 256), 256, 0, stream>>>(Wk, Wkb, 256, 136, 192);
    convert_pad<<<dim3((256 * 192 + 255) / 256), 256, 0, stream>>>(Wv, Wvb, 256, 136, 192);
    convert_pad<<<dim3((256 * 256 + 255) / 256), 256, 0, stream>>>(Wo, Wob, 256, 256, 256);
    convert_pad<<<dim3((256 * 256 + 255) / 256), 256, 0, stream>>>(W_skip, Wsb, 256, 256, 256);
    convw_reorder<<<dim3(3072), 256, 0, stream>>>(conv_w, Wcb);
    zero_pads<<<dim3(1), 256, 0, stream>>>(cinp, p1, p2, T);
    build_src_bf<<<dim3((L * KPAD + 255) / 256), 256, 0, stream>>>(input, srcb, L);

    // tgt = src @ W_proj^T   (L x 1280 == T x 256)
    gemm_bf16<false><<<dim3(1280 / 128, L / 64), 256, 0, stream>>>(
        srcb, KPAD, Wpb, 192, b_proj, tgtb, 1280, L, 1280, 192);
    // q = tgt @ Wq^T
    gemm_bf16<false><<<dim3(256 / 128, T / 64), 256, 0, stream>>>(
        tgtb, 256, Wqb, 256, bq, qb, 256, T, 256, 256);
    // k,v = src @ {Wk,Wv}^T
    gemm_bf16<false><<<dim3(256 / 128, L / 64), 256, 0, stream>>>(
        srcb, KPAD, Wkb, 192, bk, kb, 256, L, 256, 192);
    gemm_bf16<false><<<dim3(256 / 128, L / 64), 256, 0, stream>>>(
        srcb, KPAD, Wvb, 192, bv, vb, 256, L, 256, 192);

    // attention -> ctx (reuse tgtb; tgt dead after q)
    attn16<<<dim3(T / 16), 256, 0, stream>>>(qb, kb, vb, tgtb, L);

    // attn_out = ctx @ Wo^T (reuse qb)
    gemm_bf16<false><<<dim3(256 / 128, T / 64), 256, 0, stream>>>(
        tgtb, 256, Wob, 256, bo, qb, 256, T, 256, 256);

    // cnn_in = LN(attn_out) + residual -> padded rows 1..T
    ln_add_bf<<<dim3(T), 256, 0, stream>>>(qb, residual, cinp + 256);

    // conv stack as GEMMs: K=768, lda=256 (overlapping windows via padded rows)
    gemm_bf16<true><<<dim3(2, T / 64), 256, 0, stream>>>(
        cinp, 256, Wcb + 0 * 196608, 768, conv_b + 0 * 256, p1 + 256, 256, T, 256, 768);
    gemm_bf16<true><<<dim3(2, T / 64), 256, 0, stream>>>(
        p1, 256, Wcb + 1 * 196608, 768, conv_b + 1 * 256, p2 + 256, 256, T, 256, 768);
    gemm_bf16<true><<<dim3(2, T / 64), 256, 0, stream>>>(
        p2, 256, Wcb + 2 * 196608, 768, conv_b + 2 * 256, p1 + 256, 256, T, 256, 768);
    gemm_bf16<true><<<dim3(2, T / 64), 256, 0, stream>>>(
        p1, 256, Wcb + 3 * 196608, 768, conv_b + 3 * 256, p2 + 256, 256, T, 256, 768);

    // skip = cnn_in @ W_skip^T (into p1 base; conv4 done with p1)
    gemm_bf16<false><<<dim3(256 / 128, T / 64), 256, 0, stream>>>(
        cinp + 256, 256, Wsb, 256, b_skip, p1, 256, T, 256, 256);

    // out = LN(cnn_out + skip)
    ln_sum_bf<<<dim3(T), 256, 0, stream>>>(p2 + 256, p1, out);
}

// Round 3
// 126.233 us; speedup vs baseline: 6.2634x; 1.3009x over previous
//
#include <hip/hip_runtime.h>
#include <hip/hip_bf16.h>

#define PROJ 128
#define KPAD 192
#define EPS 1e-5f

typedef __attribute__((ext_vector_type(4))) float f32x4;
typedef __attribute__((ext_vector_type(8))) short bf16x8;
typedef __attribute__((ext_vector_type(4))) unsigned int u32x4;

__device__ inline float bflo(unsigned u){ union{unsigned x;float f;}c; c.x = u<<16; return c.f; }
__device__ inline float bfhi(unsigned u){ union{unsigned x;float f;}c; c.x = u & 0xffff0000u; return c.f; }
__device__ inline float bf2f(unsigned short u){ union{unsigned x;float f;}c; c.x = ((unsigned)u)<<16; return c.f; }
__device__ inline unsigned short f2bf(float f){
    union{float f; unsigned u;} c; c.f = f;
    unsigned r = c.u + 0x7fff + ((c.u >> 16) & 1);
    return (unsigned short)(r >> 16);
}

// ================= prep: all weight conversion + src build + pads, one launch ===========
__global__ __launch_bounds__(256) void prep_all(
    const float* __restrict__ W_proj, const float* __restrict__ Wq,
    const float* __restrict__ Wk, const float* __restrict__ Wv,
    const float* __restrict__ Wo, const float* __restrict__ Ws,
    const float* __restrict__ convw, const float* __restrict__ input,
    unsigned short* __restrict__ Wpb, unsigned short* __restrict__ Wqb,
    unsigned short* __restrict__ Wkb, unsigned short* __restrict__ Wvb,
    unsigned short* __restrict__ Wob, unsigned short* __restrict__ Wsb,
    unsigned short* __restrict__ Wcb, unsigned short* __restrict__ srcb,
    unsigned short* __restrict__ cinp, unsigned short* __restrict__ p1,
    unsigned short* __restrict__ p2, int L, int T)
{
    int idx = blockIdx.x * 256 + threadIdx.x;
    // segment offsets
    // [0,245760) Wpb 1280x192(136)
    if (idx < 245760) {
        int r = idx / 192, c = idx % 192;
        Wpb[idx] = (c < 136) ? f2bf(W_proj[(size_t)r * 136 + c]) : (unsigned short)0;
        return;
    }
    idx -= 245760;
    if (idx < 65536) { Wqb[idx] = f2bf(Wq[idx]); return; }
    idx -= 65536;
    if (idx < 49152) {
        int r = idx / 192, c = idx % 192;
        Wkb[idx] = (c < 136) ? f2bf(Wk[(size_t)r * 136 + c]) : (unsigned short)0;
        return;
    }
    idx -= 49152;
    if (idx < 49152) {
        int r = idx / 192, c = idx % 192;
        Wvb[idx] = (c < 136) ? f2bf(Wv[(size_t)r * 136 + c]) : (unsigned short)0;
        return;
    }
    idx -= 49152;
    if (idx < 65536) { Wob[idx] = f2bf(Wo[idx]); return; }
    idx -= 65536;
    if (idx < 65536) { Wsb[idx] = f2bf(Ws[idx]); return; }
    idx -= 65536;
    if (idx < 786432) {
        int l = idx / 196608;
        int r = idx % 196608;
        int o = r / 768, kc = r % 768;
        int kt = kc / 256, ci = kc % 256;
        Wcb[idx] = f2bf(convw[(((size_t)l * 256 + o) * 256 + ci) * 3 + kt]);
        return;
    }
    idx -= 786432;
    if (idx < L * KPAD) {
        int n = idx / KPAD, c = idx % KPAD;
        float v = 0.f;
        if (c < PROJ) v = input[(size_t)n * PROJ + c];
        else if (c < PROJ + 8) {
            int i = c - PROJ;
            int mask = (2 << i) - 1;
            v = (float)(n & mask) / (float)(1 << i);
        }
        srcb[idx] = f2bf(v);
        return;
    }
    idx -= L * KPAD;
    if (idx < 1536) {
        int buf = idx >> 9, rem = idx & 511;
        int row = rem >> 8, c = rem & 255;
        unsigned short* p = (buf == 0) ? cinp : (buf == 1) ? p1 : p2;
        size_t o = (row == 0) ? (size_t)c : (size_t)(T + 1) * 256 + c;
        p[o] = 0;
    }
}

// ================= shared 64x128 GEMM core =================
__device__ __forceinline__ void gemm_core_64x128(
    unsigned short (&As)[64][72], unsigned short (&Bs)[128][72],
    const unsigned short* __restrict__ A, int lda,
    const unsigned short* __restrict__ B, int ldb,
    const float* __restrict__ bias,
    unsigned short* __restrict__ C, int ldc,
    int K, int m0, int n0, bool do_tanh)
{
    const int tid = threadIdx.x;
    const int lane = tid & 63;
    const int wid = tid >> 6;
    const int wm = wid >> 1, wn = wid & 1;

    const int ar = tid >> 2, asg = tid & 3;   // A tile: 64 rows x 4 segs of 16
    const int br = tid >> 1, bsg = tid & 1;   // B tile: 128 rows x 2 segs of 32

    const unsigned short* Ap = A + (size_t)(m0 + ar) * lda + asg * 16;
    const unsigned short* Bp = B + (size_t)(n0 + br) * ldb + bsg * 32;

    u32x4 ra0, ra1, rb0, rb1, rb2, rb3;
    auto loadregs = [&](int k0) {
        ra0 = *(const u32x4*)(Ap + k0);
        ra1 = *(const u32x4*)(Ap + k0 + 8);
        rb0 = *(const u32x4*)(Bp + k0);
        rb1 = *(const u32x4*)(Bp + k0 + 8);
        rb2 = *(const u32x4*)(Bp + k0 + 16);
        rb3 = *(const u32x4*)(Bp + k0 + 24);
    };
    auto stlds = [&]() {
        *(u32x4*)&As[ar][asg * 16]      = ra0;
        *(u32x4*)&As[ar][asg * 16 + 8]  = ra1;
        *(u32x4*)&Bs[br][bsg * 32]      = rb0;
        *(u32x4*)&Bs[br][bsg * 32 + 8]  = rb1;
        *(u32x4*)&Bs[br][bsg * 32 + 16] = rb2;
        *(u32x4*)&Bs[br][bsg * 32 + 24] = rb3;
    };

    f32x4 acc[2][4];
    #pragma unroll
    for (int i = 0; i < 2; ++i)
        #pragma unroll
        for (int j = 0; j < 4; ++j) acc[i][j] = (f32x4){0.f, 0.f, 0.f, 0.f};

    loadregs(0);
    stlds();
    __syncthreads();

    const int rowf = lane & 15, kb = lane >> 4;
    const int ktiles = K >> 6;
    for (int kt = 0; kt < ktiles; ++kt) {
        if (kt + 1 < ktiles) loadregs((kt + 1) << 6);
        #pragma unroll
        for (int ks = 0; ks < 2; ++ks) {
            bf16x8 af[2], bfr[4];
            #pragma unroll
            for (int i = 0; i < 2; ++i)
                af[i] = *(const bf16x8*)&As[wm * 32 + i * 16 + rowf][ks * 32 + kb * 8];
            #pragma unroll
            for (int j = 0; j < 4; ++j)
                bfr[j] = *(const bf16x8*)&Bs[wn * 64 + j * 16 + rowf][ks * 32 + kb * 8];
            #pragma unroll
            for (int i = 0; i < 2; ++i)
                #pragma unroll
                for (int j = 0; j < 4; ++j)
                    acc[i][j] = __builtin_amdgcn_mfma_f32_16x16x32_bf16(af[i], bfr[j], acc[i][j], 0, 0, 0);
        }
        __syncthreads();
        if (kt + 1 < ktiles) { stlds(); __syncthreads(); }
    }

    const int rq = lane >> 4;
    #pragma unroll
    for (int i = 0; i < 2; ++i) {
        int gm = m0 + wm * 32 + i * 16 + rq * 4;
        #pragma unroll
        for (int j = 0; j < 4; ++j) {
            int gn = n0 + wn * 64 + j * 16 + rowf;
            float bv = bias[gn];
            #pragma unroll
            for (int r = 0; r < 4; ++r) {
                float vv = acc[i][j][r] + bv;
                if (do_tanh) vv = 1.f - 2.f / (__expf(2.f * vv) + 1.f);
                C[(size_t)(gm + r) * ldc + gn] = f2bf(vv);
            }
        }
    }
}

template<bool TANH>
__global__ __launch_bounds__(256) void gemm_bf16(
    const unsigned short* __restrict__ A, int lda,
    const unsigned short* __restrict__ B, int ldb,
    const float* __restrict__ bias,
    unsigned short* __restrict__ C, int ldc, int K)
{
    __shared__ unsigned short As[64][72];
    __shared__ unsigned short Bs[128][72];
    gemm_core_64x128(As, Bs, A, lda, B, ldb, bias, C, ldc, K,
                     blockIdx.y * 64, blockIdx.x * 128, TANH);
}

// q/k/v in one launch: blocks [0,320)=q, [320,384)=k, [384,448)=v
__global__ __launch_bounds__(256) void qkv_fused(
    const unsigned short* __restrict__ tgt,
    const unsigned short* __restrict__ src,
    const unsigned short* __restrict__ Wqb,
    const unsigned short* __restrict__ Wkb,
    const unsigned short* __restrict__ Wvb,
    const float* __restrict__ bq, const float* __restrict__ bk,
    const float* __restrict__ bv,
    unsigned short* __restrict__ qb, unsigned short* __restrict__ kb,
    unsigned short* __restrict__ vb)
{
    __shared__ unsigned short As[64][72];
    __shared__ unsigned short Bs[128][72];
    int bi = blockIdx.x;
    const unsigned short *A, *B;
    const float* bias;
    unsigned short* C;
    int lda, K, m0, n0;
    if (bi < 320) {
        A = tgt; B = Wqb; bias = bq; C = qb; lda = 256; K = 256;
        m0 = (bi >> 1) * 64; n0 = (bi & 1) * 128;
    } else if (bi < 384) {
        int t = bi - 320;
        A = src; B = Wkb; bias = bk; C = kb; lda = KPAD; K = 192;
        m0 = (t >> 1) * 64; n0 = (t & 1) * 128;
    } else {
        int t = bi - 384;
        A = src; B = Wvb; bias = bv; C = vb; lda = KPAD; K = 192;
        m0 = (t >> 1) * 64; n0 = (t & 1) * 128;
    }
    gemm_core_64x128(As, Bs, A, lda, B, K == 192 ? 192 : 256, bias, C, 256, K, m0, n0, false);
}

// ================= 64x256-tile GEMM with fused LayerNorm epilogue =================
// MODE 0: cinp[gm+1] = f2bf( LN(acc + bias) + residual[gm] )        (bf16 out, padded)
// MODE 1: out[gm]    = LN( (acc + bias) + bf2f(cnnout[gm+1]) )      (f32 out)
template<int MODE>
__global__ __launch_bounds__(512) void gemm_ln(
    const unsigned short* __restrict__ A, int lda,
    const unsigned short* __restrict__ B,         // ldb = 256, K = 256
    const float* __restrict__ bias,
    const float* __restrict__ residual,
    const unsigned short* __restrict__ cnnout,
    unsigned short* __restrict__ out_bf,
    float* __restrict__ out_f32)
{
    __shared__ unsigned short As[64][72];
    __shared__ unsigned short Bs[256][72];
    __shared__ float redS[64][4];
    __shared__ float redQ[64][4];

    const int tid = threadIdx.x;
    const int lane = tid & 63;
    const int wid = tid >> 6;
    const int wm = wid >> 2, wn = wid & 3;       // 2 x 4 wave grid, wave = 32x64
    const int m0 = blockIdx.x * 64;

    const int arow = tid >> 3, acol = (tid & 7) * 8;
    const int brow = tid >> 1, bcol = (tid & 1) * 32;
    const unsigned short* Ap = A + (size_t)(m0 + arow) * lda + acol;
    const unsigned short* Bp = B + (size_t)brow * 256 + bcol;

    u32x4 ra, rb0, rb1, rb2, rb3;
    auto loadregs = [&](int k0) {
        ra  = *(const u32x4*)(Ap + k0);
        rb0 = *(const u32x4*)(Bp + k0);
        rb1 = *(const u32x4*)(Bp + k0 + 8);
        rb2 = *(const u32x4*)(Bp + k0 + 16);
        rb3 = *(const u32x4*)(Bp + k0 + 24);
    };
    auto stlds = [&]() {
        *(u32x4*)&As[arow][acol]       = ra;
        *(u32x4*)&Bs[brow][bcol]       = rb0;
        *(u32x4*)&Bs[brow][bcol + 8]   = rb1;
        *(u32x4*)&Bs[brow][bcol + 16]  = rb2;
        *(u32x4*)&Bs[brow][bcol + 24]  = rb3;
    };

    f32x4 acc[2][4];
    #pragma unroll
    for (int i = 0; i < 2; ++i)
        #pragma unroll
        for (int j = 0; j < 4; ++j) acc[i][j] = (f32x4){0.f, 0.f, 0.f, 0.f};

    loadregs(0);
    stlds();
    __syncthreads();

    const int rowf = lane & 15, kb = lane >> 4;
    #pragma unroll
    for (int kt = 0; kt < 4; ++kt) {
        if (kt < 3) loadregs((kt + 1) << 6);
        #pragma unroll
        for (int ks = 0; ks < 2; ++ks) {
            bf16x8 af[2], bfr[4];
            #pragma unroll
            for (int i = 0; i < 2; ++i)
                af[i] = *(const bf16x8*)&As[wm * 32 + i * 16 + rowf][ks * 32 + kb * 8];
            #pragma unroll
            for (int j = 0; j < 4; ++j)
                bfr[j] = *(const bf16x8*)&Bs[wn * 64 + j * 16 + rowf][ks * 32 + kb * 8];
            #pragma unroll
            for (int i = 0; i < 2; ++i)
                #pragma unroll
                for (int j = 0; j < 4; ++j)
                    acc[i][j] = __builtin_amdgcn_mfma_f32_16x16x32_bf16(af[i], bfr[j], acc[i][j], 0, 0, 0);
        }
        __syncthreads();
        if (kt < 3) { stlds(); __syncthreads(); }
    }

    // values v[i][j][r] at row (wm*32+i*16+rq*4+r), col (wn*64+j*16+rowf)
    const int rq = lane >> 4;
    float val[2][4][4];
    #pragma unroll
    for (int i = 0; i < 2; ++i)
        #pragma unroll
        for (int j = 0; j < 4; ++j) {
            int gn = wn * 64 + j * 16 + rowf;
            float bv = bias[gn];
            #pragma unroll
            for (int r = 0; r < 4; ++r) {
                float vv = acc[i][j][r] + bv;
                if (MODE == 1) {
                    int gm = m0 + wm * 32 + i * 16 + rq * 4 + r;
                    vv += bf2f(cnnout[(size_t)(gm + 1) * 256 + gn]);
                }
                val[i][j][r] = vv;
            }
        }

    // row sums / sumsq: reduce j (in-thread), then 16 lanes (rowf), then 4 wn waves via LDS
    #pragma unroll
    for (int i = 0; i < 2; ++i)
        #pragma unroll
        for (int r = 0; r < 4; ++r) {
            float s = val[i][0][r] + val[i][1][r] + val[i][2][r] + val[i][3][r];
            float q = val[i][0][r] * val[i][0][r] + val[i][1][r] * val[i][1][r]
                    + val[i][2][r] * val[i][2][r] + val[i][3][r] * val[i][3][r];
            #pragma unroll
            for (int m = 1; m < 16; m <<= 1) {
                s += __shfl_xor(s, m, 64);
                q += __shfl_xor(q, m, 64);
            }
            if (rowf == 0) {
                int row = wm * 32 + i * 16 + rq * 4 + r;
                redS[row][wn] = s;
                redQ[row][wn] = q;
            }
        }
    __syncthreads();

    #pragma unroll
    for (int i = 0; i < 2; ++i) {
        #pragma unroll
        for (int r = 0; r < 4; ++r) {
            int row = wm * 32 + i * 16 + rq * 4 + r;
            int gm = m0 + row;
            float s = redS[row][0] + redS[row][1] + redS[row][2] + redS[row][3];
            float q = redQ[row][0] + redQ[row][1] + redQ[row][2] + redQ[row][3];
            float mu = s * (1.f / 256.f);
            float var = q * (1.f / 256.f) - mu * mu;
            float rs = rsqrtf(var + EPS);
            #pragma unroll
            for (int j = 0; j < 4; ++j) {
                int gn = wn * 64 + j * 16 + rowf;
                float nv = (val[i][j][r] - mu) * rs;
                if (MODE == 0) {
                    nv += residual[(size_t)gm * 256 + gn];
                    out_bf[(size_t)(gm + 1) * 256 + gn] = f2bf(nv);
                } else {
                    out_f32[(size_t)gm * 256 + gn] = nv;
                }
            }
        }
    }
}

// ================= banded attention (unchanged) =================
__global__ __launch_bounds__(256) void attn16(
    const unsigned short* __restrict__ q,
    const unsigned short* __restrict__ k,
    const unsigned short* __restrict__ v,
    unsigned short* __restrict__ ctx, int L)
{
    __shared__ unsigned short ksm[30][264];
    __shared__ unsigned short vsm[30][264];
    const int j0 = blockIdx.x * 16;
    const int iblk0 = (j0 >= 68) ? (j0 - 64) / 5 : 0;
    int ihim = (j0 + 79) / 5; if (ihim > L - 1) ihim = L - 1;
    const int NR = ihim - iblk0 + 1;

    for (int e = threadIdx.x; e < 30 * 32; e += 256) {
        int rr = e >> 5, cc = (e & 31) * 8;
        u32x4 kz = {0, 0, 0, 0}, vz = {0, 0, 0, 0};
        if (rr < NR) {
            kz = *(const u32x4*)&k[(size_t)(iblk0 + rr) * 256 + cc];
            vz = *(const u32x4*)&v[(size_t)(iblk0 + rr) * 256 + cc];
        }
        *(u32x4*)&ksm[rr][cc] = kz;
        *(u32x4*)&vsm[rr][cc] = vz;
    }
    __syncthreads();

    const int tid = threadIdx.x;
    const int h = tid >> 6, lane = tid & 63;
    const int qq = lane & 15, p = lane >> 4;
    const int j = j0 + qq;
    const int colb = h * 64 + p * 16;

    float qr[16];
    {
        u32x4 q0 = *(const u32x4*)&q[(size_t)j * 256 + colb];
        u32x4 q1 = *(const u32x4*)&q[(size_t)j * 256 + colb + 8];
        #pragma unroll
        for (int w = 0; w < 4; ++w) {
            qr[2 * w]     = bflo(q0[w]) * 0.125f;
            qr[2 * w + 1] = bfhi(q0[w]) * 0.125f;
            qr[8 + 2 * w]     = bflo(q1[w]) * 0.125f;
            qr[8 + 2 * w + 1] = bfhi(q1[w]) * 0.125f;
        }
    }
    const int ilo = (j >= 68) ? (j - 64) / 5 : 0;
    int ihi = (j + 64) / 5; if (ihi > L - 1) ihi = L - 1;

    float sc[30];
    #pragma unroll
    for (int t = 0; t < 30; ++t) {
        int i = iblk0 + t;
        u32x4 k0 = *(const u32x4*)&ksm[t][colb];
        u32x4 k1 = *(const u32x4*)&ksm[t][colb + 8];
        float s = 0.f;
        #pragma unroll
        for (int w = 0; w < 4; ++w) {
            s += qr[2 * w]     * bflo(k0[w]);
            s += qr[2 * w + 1] * bfhi(k0[w]);
            s += qr[8 + 2 * w]     * bflo(k1[w]);
            s += qr[8 + 2 * w + 1] * bfhi(k1[w]);
        }
        s += __shfl_xor(s, 16, 64);
        s += __shfl_xor(s, 32, 64);
        sc[t] = (i >= ilo && i <= ihi) ? s : -1e30f;
    }
    float mx = -1e30f;
    #pragma unroll
    for (int t = 0; t < 30; ++t) mx = fmaxf(mx, sc[t]);
    float den = 0.f, o[16];
    #pragma unroll
    for (int d = 0; d < 16; ++d) o[d] = 0.f;
    #pragma unroll
    for (int t = 0; t < 30; ++t) {
        float pt = __expf(sc[t] - mx);
        den += pt;
        u32x4 v0 = *(const u32x4*)&vsm[t][colb];
        u32x4 v1 = *(const u32x4*)&vsm[t][colb + 8];
        #pragma unroll
        for (int w = 0; w < 4; ++w) {
            o[2 * w]     += pt * bflo(v0[w]);
            o[2 * w + 1] += pt * bfhi(v0[w]);
            o[8 + 2 * w]     += pt * bflo(v1[w]);
            o[8 + 2 * w + 1] += pt * bfhi(v1[w]);
        }
    }
    float inv = 1.f / den;
    #pragma unroll
    for (int d = 0; d < 16; ++d)
        ctx[(size_t)j * 256 + colb + d] = f2bf(o[d] * inv);
}

extern "C" void kernel_launch(void* const* d_in, const int* in_sizes, int n_in,
                              void* d_out, int out_size, void* d_ws, size_t ws_size,
                              hipStream_t stream) {
    const float* input    = (const float*)d_in[0];
    const float* residual = (const float*)d_in[1];
    const float* W_proj   = (const float*)d_in[2];
    const float* b_proj   = (const float*)d_in[3];
    const float* Wq       = (const float*)d_in[4];
    const float* bq       = (const float*)d_in[5];
    const float* Wk       = (const float*)d_in[6];
    const float* bk       = (const float*)d_in[7];
    const float* Wv       = (const float*)d_in[8];
    const float* bv       = (const float*)d_in[9];
    const float* Wo       = (const float*)d_in[10];
    const float* bo       = (const float*)d_in[11];
    const float* conv_w   = (const float*)d_in[12];
    const float* conv_b   = (const float*)d_in[13];
    const float* W_skip   = (const float*)d_in[14];
    const float* b_skip   = (const float*)d_in[15];
    float* out = (float*)d_out;

    const int L = in_sizes[0] / PROJ;   // 2048
    const int T = 5 * L;                // 10240

    unsigned short* w16 = (unsigned short*)d_ws;
    size_t off = 0;
    auto alloc = [&](size_t n) { unsigned short* p = w16 + off; off += n; return p; };
    unsigned short* Wpb  = alloc((size_t)1280 * 192);      // 245760
    unsigned short* Wqb  = alloc(256 * 256);
    unsigned short* Wkb  = alloc(256 * 192);
    unsigned short* Wvb  = alloc(256 * 192);
    unsigned short* Wob  = alloc(256 * 256);
    unsigned short* Wsb  = alloc(256 * 256);
    unsigned short* Wcb  = alloc((size_t)4 * 256 * 768);
    unsigned short* srcb = alloc((size_t)L * KPAD);
    unsigned short* tgtb = alloc((size_t)T * 256);         // tgt, then ctx
    unsigned short* qb   = alloc((size_t)T * 256);         // q
    unsigned short* kb   = alloc((size_t)L * 256);
    unsigned short* vb   = alloc((size_t)L * 256);
    unsigned short* cinp = alloc((size_t)(T + 2) * 256);   // padded cnn_in
    unsigned short* p1   = alloc((size_t)(T + 2) * 256);   // conv ping
    unsigned short* p2   = alloc((size_t)(T + 2) * 256);   // conv pong

    // 1) prep: all conversions + src + pads (1721856 elements = 6726 blocks)
    prep_all<<<dim3(6726), 256, 0, stream>>>(
        W_proj, Wq, Wk, Wv, Wo, W_skip, conv_w, input,
        Wpb, Wqb, Wkb, Wvb, Wob, Wsb, Wcb, srcb, cinp, p1, p2, L, T);

    // 2) tgt = src @ W_proj^T  (L x 1280 == T x 256)
    gemm_bf16<false><<<dim3(1280 / 128, L / 64), 256, 0, stream>>>(
        srcb, KPAD, Wpb, 192, b_proj, tgtb, 1280, 192);

    // 3) q/k/v fused
    qkv_fused<<<dim3(448), 256, 0, stream>>>(
        tgtb, srcb, Wqb, Wkb, Wvb, bq, bk, bv, qb, kb, vb);

    // 4) attention -> ctx (reuse tgtb)
    attn16<<<dim3(T / 16), 256, 0, stream>>>(qb, kb, vb, tgtb, L);

    // 5) cnn_in = LN(ctx @ Wo^T + bo) + residual  (fused, writes cinp rows 1..T)
    gemm_ln<0><<<dim3(T / 64), 512, 0, stream>>>(
        tgtb, 256, Wob, bo, residual, nullptr, cinp, nullptr);

    // 6-9) conv stack as GEMMs: K=768, lda=256 (overlapping windows via padded rows)
    gemm_bf16<true><<<dim3(2, T / 64), 256, 0, stream>>>(
        cinp, 256, Wcb + 0 * 196608, 768, conv_b + 0 * 256, p1 + 256, 256, 768);
    gemm_bf16<true><<<dim3(2, T / 64), 256, 0, stream>>>(
        p1, 256, Wcb + 1 * 196608, 768, conv_b + 1 * 256, p2 + 256, 256, 768);
    gemm_bf16<true><<<dim3(2, T / 64), 256, 0, stream>>>(
        p2, 256, Wcb + 2 * 196608, 768, conv_b + 2 * 256, p1 + 256, 256, 768);
    gemm_bf16<true><<<dim3(2, T / 64), 256, 0, stream>>>(
        p1, 256, Wcb + 3 * 196608, 768, conv_b + 3 * 256, p2 + 256, 256, 768);

    // 10) out = LN(cnn_out + cnn_in @ W_skip^T + b_skip)  (fused, f32 out)
    gemm_ln<1><<<dim3(T / 64), 512, 0, stream>>>(
        cinp + 256, 256, Wsb, b_skip, nullptr, p2, nullptr, out);
}